// Round 1
// baseline (3670.124 us; speedup 1.0000x reference)
//
#include <hip/hip_runtime.h>
#include <cstdint>
#include <cstddef>

// ---------------------------------------------------------------------------
// MDHP-LSTM on MI355X.
// S=512, B=128, D=256, H=512. Output: outputs[S,B,H] ++ h_T[B,H] ++ c_T[B,H].
//
// Strategy: single persistent kernel; 8 independent batch-chains (16 rows) x
// 32 column-workgroups (16 h-cols = 64 gate-cols) = 256 WGs, one per CU.
// [W;U]^T staged in LDS as bf16 once; per step 24 mfma_16x16x32_bf16 per wave
// (wave = gate). h_{t-1} is read from d_out itself (outputs ARE the h history).
// Producer->consumer sync: agent-scope write-through stores + per-(chain,t)
// counter; consumers poll relaxed (fill-on-demand => no stale-cache hazard).
// ---------------------------------------------------------------------------

typedef __attribute__((ext_vector_type(8))) short short8;
typedef __attribute__((ext_vector_type(4))) float floatx4;

#define SEQ 512
#define BATCH 128
#define DIN 256
#define HID 512
#define KTOT 768              // D + H
#define NCHAIN 8              // batch chains (16 rows each)
#define NCOLW 32              // col-WGs per chain (16 h-cols each)
#define BS_STRIDE 776         // shorts per LDS B-row (768 + 8 pad, 16B aligned)

__device__ __forceinline__ short f2bf(float f) {
  union { float f; unsigned u; } v; v.f = f;
  unsigned u = v.u + 0x7fffu + ((v.u >> 16) & 1u);   // RNE
  return (short)(u >> 16);
}

// ---- prep: GT[n][k] = bf16 of (k<256 ? W_g[k][hc] : U_g[k-256][hc]), n=g*512+hc
__global__ void prep_gt(const float* __restrict__ Wi, const float* __restrict__ Ui,
                        const float* __restrict__ Wf, const float* __restrict__ Uf,
                        const float* __restrict__ Wc, const float* __restrict__ Uc,
                        const float* __restrict__ Wo, const float* __restrict__ Uo,
                        short* __restrict__ GT) {
  int idx = blockIdx.x * 256 + threadIdx.x;
  if (idx >= 2048 * KTOT) return;
  int n = idx / KTOT, k = idx % KTOT;
  int g = n >> 9, hc = n & 511;
  const float* W; const float* U;
  if (g == 0)      { W = Wi; U = Ui; }
  else if (g == 1) { W = Wf; U = Uf; }
  else if (g == 2) { W = Wc; U = Uc; }
  else             { W = Wo; U = Uo; }
  float v = (k < DIN) ? W[k * HID + hc] : U[(k - DIN) * HID + hc];
  GT[idx] = f2bf(v);
}

// ---- prep: mdhp[b][h] = tanh(alpha@A - (beta*tspan)@B + theta@C)  (fp32 exact)
__global__ void prep_mdhp(const float* __restrict__ alpha, const float* __restrict__ beta,
                          const float* __restrict__ theta, const float* __restrict__ tspan,
                          const float* __restrict__ A, const float* __restrict__ Bm,
                          const float* __restrict__ C, float* __restrict__ mdhp) {
  int idx = blockIdx.x * 256 + threadIdx.x;     // 65536
  int b = idx >> 9, h = idx & 511;
  float ts = tspan[b];
  float acc = 0.f;
  for (int k = 0; k < 256; ++k)
    acc += alpha[b * 256 + k] * A[k * HID + h] - ts * beta[b * 256 + k] * Bm[k * HID + h];
  for (int k = 0; k < 16; ++k)
    acc += theta[b * 16 + k] * C[k * HID + h];
  mdhp[idx] = tanhf(acc);
}

__global__ void zero_cnt(int* __restrict__ cnt) {
  int idx = blockIdx.x * 256 + threadIdx.x;
  if (idx < NCHAIN * SEQ) cnt[idx] = 0;
}

// ---- the persistent recurrence kernel --------------------------------------
__global__ __launch_bounds__(256, 1) void lstm_persist(
    const float* __restrict__ x, const float* __restrict__ h0,
    const float* __restrict__ c0,
    const float* __restrict__ bi, const float* __restrict__ bf_,
    const float* __restrict__ bc, const float* __restrict__ bo,
    const short* __restrict__ GT, const float* __restrict__ mdhp,
    int* cnt, float* out) {
  // 64 B-rows (4 gates x 16 cols) x 776 shorts = 99,328 B
  __shared__ __align__(16) short Bs[64 * BS_STRIDE];
  __shared__ float gbuf[4][16][16];
  __shared__ float carr[16][16];
  __shared__ float md_s[16][16];
  __shared__ float bias_s[4][16];

  const int tid = threadIdx.x;
  const int wg = blockIdx.x;
  const int chain = wg & 7;        // likely XCD-local if round-robin mapping
  const int j = wg >> 3;           // 0..31 column group

  // stage B^T slice: local row lr = g*16+c  <-  GT row n = g*512 + j*16 + c
  for (int idx = tid; idx < 64 * 384; idx += 256) {
    int lr = idx / 384, dw = idx % 384;
    int n = ((lr >> 4) << 9) + (j << 4) + (lr & 15);
    ((int*)Bs)[lr * 388 + dw] = ((const int*)GT)[n * 384 + dw];
  }
  {
    int r = tid >> 4, c = tid & 15;
    int b = (chain << 4) + r, hc = (j << 4) + c;
    carr[r][c] = c0[b * HID + hc];
    md_s[r][c] = mdhp[b * HID + hc];
    if (tid < 64) {
      int g = tid >> 4, cc = tid & 15;
      const float* bp = (g == 0) ? bi : (g == 1) ? bf_ : (g == 2) ? bc : bo;
      bias_s[g][cc] = bp[(j << 4) + cc];
    }
  }
  __syncthreads();

  const int lane = tid & 63;
  const int g = tid >> 6;                 // wave = gate
  const int mr = lane & 15;               // A-row / B-col within tile
  const int q = lane >> 4;                // quad
  const int bglob = (chain << 4) + mr;    // global batch row for A-frags
  const short* Brow = &Bs[(g * 16 + mr) * BS_STRIDE + q * 8];
  int* mycnt = cnt + chain * SEQ;

  for (int t = 0; t < SEQ; ++t) {
    floatx4 acc = {0.f, 0.f, 0.f, 0.f};

    // ---- x @ W part (h-independent: runs while producers of h_{t-1} finish)
    const float4* xp = reinterpret_cast<const float4*>(
        x + ((size_t)t * BATCH + bglob) * DIN + q * 8);
#pragma unroll
    for (int kk = 0; kk < 8; ++kk) {
      float4 v0 = xp[kk * 8];
      float4 v1 = xp[kk * 8 + 1];
      short8 af;
      af[0] = f2bf(v0.x); af[1] = f2bf(v0.y); af[2] = f2bf(v0.z); af[3] = f2bf(v0.w);
      af[4] = f2bf(v1.x); af[5] = f2bf(v1.y); af[6] = f2bf(v1.z); af[7] = f2bf(v1.w);
      short8 bfr = *(const short8*)(Brow + kk * 32);
      acc = __builtin_amdgcn_mfma_f32_16x16x32_bf16(af, bfr, acc, 0, 0, 0);
    }

    // ---- wait for full h_{t-1} of this chain
    if (t > 0) {
      if (tid == 0) {
        while (__hip_atomic_load(&mycnt[t - 1], __ATOMIC_RELAXED,
                                 __HIP_MEMORY_SCOPE_AGENT) < NCOLW)
          __builtin_amdgcn_s_sleep(2);
      }
      __syncthreads();
    }

    // ---- h @ U part
    const float* hbase = (t == 0)
        ? (h0 + (size_t)bglob * HID)
        : (out + ((size_t)(t - 1) * BATCH + bglob) * HID);
    const float4* hp = reinterpret_cast<const float4*>(hbase + q * 8);
#pragma unroll
    for (int kk = 0; kk < 16; ++kk) {
      float4 v0 = hp[kk * 8];
      float4 v1 = hp[kk * 8 + 1];
      short8 af;
      af[0] = f2bf(v0.x); af[1] = f2bf(v0.y); af[2] = f2bf(v0.z); af[3] = f2bf(v0.w);
      af[4] = f2bf(v1.x); af[5] = f2bf(v1.y); af[6] = f2bf(v1.z); af[7] = f2bf(v1.w);
      short8 bfr = *(const short8*)(Brow + DIN + kk * 32);
      acc = __builtin_amdgcn_mfma_f32_16x16x32_bf16(af, bfr, acc, 0, 0, 0);
    }

    // ---- epilogue: gates -> c,h ; C/D layout: col=lane&15, row=q*4+i (m89)
#pragma unroll
    for (int i = 0; i < 4; ++i) gbuf[g][q * 4 + i][mr] = acc[i];
    __syncthreads();
    {
      int r = tid >> 4, c = tid & 15;
      float gi = gbuf[0][r][c] + bias_s[0][c];
      float gf = gbuf[1][r][c] + bias_s[1][c];
      float gc = gbuf[2][r][c] + bias_s[2][c];
      float go = gbuf[3][r][c] + bias_s[3][c];
      float it = 1.f / (1.f + expf(-gi));
      float ft = 1.f / (1.f + expf(-gf));
      float ot = 1.f / (1.f + expf(-go));
      float ch = tanhf(gc);
      float cn = md_s[r][c] * (ft * carr[r][c] + it * ch);
      carr[r][c] = cn;
      float hv = ot * tanhf(cn);
      size_t oidx = ((size_t)t * BATCH + (chain << 4) + r) * HID + (j << 4) + c;
      // write-through (agent scope) so other XCDs' demand fills see it at LLC
      __hip_atomic_store(&out[oidx], hv, __ATOMIC_RELAXED, __HIP_MEMORY_SCOPE_AGENT);
      if (t == SEQ - 1) {
        size_t base = (size_t)SEQ * BATCH * HID;
        int e = ((chain << 4) + r) * HID + (j << 4) + c;
        out[base + e] = hv;                    // h_T
        out[base + BATCH * HID + e] = cn;      // c_T
      }
    }
    __syncthreads();  // drains vmcnt for ALL waves before the flag
    if (tid == 0)
      __hip_atomic_fetch_add(&mycnt[t], 1, __ATOMIC_RELAXED,
                             __HIP_MEMORY_SCOPE_AGENT);
  }
}

// ---------------------------------------------------------------------------
extern "C" void kernel_launch(void* const* d_in, const int* in_sizes, int n_in,
                              void* d_out, int out_size, void* d_ws, size_t ws_size,
                              hipStream_t stream) {
  const float* x     = (const float*)d_in[0];
  const float* h0    = (const float*)d_in[1];
  const float* c0    = (const float*)d_in[2];
  const float* alpha = (const float*)d_in[3];
  const float* beta  = (const float*)d_in[4];
  const float* theta = (const float*)d_in[5];
  const float* tspan = (const float*)d_in[6];
  const float* Amd   = (const float*)d_in[7];
  const float* Bmd   = (const float*)d_in[8];
  const float* Cmd   = (const float*)d_in[9];
  const float* Wi = (const float*)d_in[10]; const float* Ui = (const float*)d_in[11];
  const float* bi = (const float*)d_in[12];
  const float* Wf = (const float*)d_in[13]; const float* Uf = (const float*)d_in[14];
  const float* bf_ = (const float*)d_in[15];
  const float* Wc = (const float*)d_in[16]; const float* Uc = (const float*)d_in[17];
  const float* bc = (const float*)d_in[18];
  const float* Wo = (const float*)d_in[19]; const float* Uo = (const float*)d_in[20];
  const float* bo = (const float*)d_in[21];

  float* out = (float*)d_out;
  char* ws = (char*)d_ws;
  short* GT   = (short*)ws;                                   // 2048*768*2 = 3,145,728 B
  float* mdhp = (float*)(ws + 3145728);                       // 65536*4    =   262,144 B
  int*   cnt  = (int*)(ws + 3145728 + 262144);                // 8*512*4    =    16,384 B

  zero_cnt<<<16, 256, 0, stream>>>(cnt);
  prep_gt<<<(2048 * KTOT + 255) / 256, 256, 0, stream>>>(Wi, Ui, Wf, Uf, Wc, Uc, Wo, Uo, GT);
  prep_mdhp<<<256, 256, 0, stream>>>(alpha, beta, theta, tspan, Amd, Bmd, Cmd, mdhp);
  lstm_persist<<<NCHAIN * NCOLW, 256, 0, stream>>>(x, h0, c0, bi, bf_, bc, bo,
                                                   GT, mdhp, cnt, out);
}

// Round 2
// 2195.077 us; speedup vs baseline: 1.6720x; 1.6720x over previous
//
#include <hip/hip_runtime.h>
#include <cstdint>
#include <cstddef>

// ---------------------------------------------------------------------------
// MDHP-LSTM on MI355X.  S=512, B=128, D=256, H=512.
// Output: outputs[S,B,H] ++ h_T[B,H] ++ c_T[B,H].
//
// Persistent kernel: 8 batch-chains (16 rows) x 32 col-WGs (16 h-cols) = 256
// WGs, 1/CU. [W;U]^T in LDS bf16. Per step/wave: 24 mfma_16x16x32_bf16.
// Round-2 deltas vs round-1:
//   * x pre-converted to bf16 (xb) -> no per-step f2bf on the x path
//   * h ring-buffer hbuf[t] in bf16 (slot 0 = h0) -> consumers load bf16
//     A-frags directly; producer converts once/elem (shuffle-paired 4B store)
//   * per-step order: issue x-frag loads -> poll -> issue h-frag loads ->
//     x MFMAs (hide h latency) -> h MFMAs -> epilogue
//   * gbuf padded [16][17] (was 4-way bank conflicted), fast exp/tanh
// ---------------------------------------------------------------------------

typedef __attribute__((ext_vector_type(8))) short short8;
typedef __attribute__((ext_vector_type(4))) float floatx4;

#define SEQ 512
#define BATCH 128
#define DIN 256
#define HID 512
#define KTOT 768
#define NCHAIN 8
#define NCOLW 32
#define BS_STRIDE 776         // shorts per LDS B-row (768 + 8 pad, 16B aligned)

__device__ __forceinline__ short f2bf(float f) {
  union { float f; unsigned u; } v; v.f = f;
  unsigned u = v.u + 0x7fffu + ((v.u >> 16) & 1u);   // RNE
  return (short)(u >> 16);
}
__device__ __forceinline__ float fsig(float x) {
  return 1.f / (1.f + __expf(-x));
}
__device__ __forceinline__ float ftanh(float x) {
  float a = fabsf(x);
  float e = __expf(-2.f * a);
  float r = (1.f - e) / (1.f + e);
  return copysignf(r, x);
}

// ---- prep: GT[n][k] = bf16 of (k<256 ? W_g[k][hc] : U_g[k-256][hc]), n=g*512+hc
__global__ void prep_gt(const float* __restrict__ Wi, const float* __restrict__ Ui,
                        const float* __restrict__ Wf, const float* __restrict__ Uf,
                        const float* __restrict__ Wc, const float* __restrict__ Uc,
                        const float* __restrict__ Wo, const float* __restrict__ Uo,
                        short* __restrict__ GT) {
  int idx = blockIdx.x * 256 + threadIdx.x;
  if (idx >= 2048 * KTOT) return;
  int n = idx / KTOT, k = idx % KTOT;
  int g = n >> 9, hc = n & 511;
  const float* W; const float* U;
  if (g == 0)      { W = Wi; U = Ui; }
  else if (g == 1) { W = Wf; U = Uf; }
  else if (g == 2) { W = Wc; U = Uc; }
  else             { W = Wo; U = Uo; }
  float v = (k < DIN) ? W[k * HID + hc] : U[(k - DIN) * HID + hc];
  GT[idx] = f2bf(v);
}

// ---- prep: x -> bf16 (4 elems/thread)
__global__ void prep_xb(const float* __restrict__ x, short* __restrict__ xb) {
  int idx = blockIdx.x * 256 + threadIdx.x;           // 4,194,304
  float4 v = ((const float4*)x)[idx];
  short4 o; o.x = f2bf(v.x); o.y = f2bf(v.y); o.z = f2bf(v.z); o.w = f2bf(v.w);
  ((short4*)xb)[idx] = o;
}

// ---- prep: h0 -> hbuf slot 0 (bf16)
__global__ void prep_h0(const float* __restrict__ h0, short* __restrict__ hbuf) {
  int idx = blockIdx.x * 256 + threadIdx.x;           // 65536
  hbuf[idx] = f2bf(h0[idx]);
}

// ---- prep: mdhp[b][h] = tanh(alpha@A - (beta*tspan)@B + theta@C)  (fp32)
__global__ void prep_mdhp(const float* __restrict__ alpha, const float* __restrict__ beta,
                          const float* __restrict__ theta, const float* __restrict__ tspan,
                          const float* __restrict__ A, const float* __restrict__ Bm,
                          const float* __restrict__ C, float* __restrict__ mdhp) {
  int idx = blockIdx.x * 256 + threadIdx.x;           // 65536
  int b = idx >> 9, h = idx & 511;
  float ts = tspan[b];
  float acc = 0.f;
  for (int k = 0; k < 256; ++k)
    acc += alpha[b * 256 + k] * A[k * HID + h] - ts * beta[b * 256 + k] * Bm[k * HID + h];
  for (int k = 0; k < 16; ++k)
    acc += theta[b * 16 + k] * C[k * HID + h];
  mdhp[idx] = tanhf(acc);
}

__global__ void zero_cnt(int* __restrict__ cnt) {
  int idx = blockIdx.x * 256 + threadIdx.x;
  if (idx < NCHAIN * SEQ) cnt[idx] = 0;
}

// ---- the persistent recurrence kernel --------------------------------------
__global__ __launch_bounds__(256, 1) void lstm_persist(
    const short* __restrict__ xb, const float* __restrict__ c0,
    const float* __restrict__ bi, const float* __restrict__ bf_,
    const float* __restrict__ bc, const float* __restrict__ bo,
    const short* __restrict__ GT, const float* __restrict__ mdhp,
    int* cnt, short* hbuf, float* out) {
  __shared__ __align__(16) short Bs[64 * BS_STRIDE];   // 99,328 B
  __shared__ float gbuf[4][16][17];                    // padded: no 4-way conflicts
  __shared__ float carr[16][16];
  __shared__ float md_s[16][16];
  __shared__ float bias_s[4][16];

  const int tid = threadIdx.x;
  const int wg = blockIdx.x;
  const int chain = wg & 7;        // likely XCD-local under round-robin mapping
  const int j = wg >> 3;           // 0..31 column group

  // stage B^T slice: local row lr = g*16+c  <-  GT row n = g*512 + j*16 + c
  for (int idx = tid; idx < 64 * 384; idx += 256) {
    int lr = idx / 384, dw = idx % 384;
    int n = ((lr >> 4) << 9) + (j << 4) + (lr & 15);
    ((int*)Bs)[lr * 388 + dw] = ((const int*)GT)[n * 384 + dw];
  }
  {
    int r = tid >> 4, c = tid & 15;
    int b = (chain << 4) + r, hc = (j << 4) + c;
    carr[r][c] = c0[b * HID + hc];
    md_s[r][c] = mdhp[b * HID + hc];
    if (tid < 64) {
      int g = tid >> 4, cc = tid & 15;
      const float* bp = (g == 0) ? bi : (g == 1) ? bf_ : (g == 2) ? bc : bo;
      bias_s[g][cc] = bp[(j << 4) + cc];
    }
  }
  __syncthreads();

  const int lane = tid & 63;
  const int g = tid >> 6;                 // wave = gate
  const int mr = lane & 15;               // A-row / B-col within tile
  const int q = lane >> 4;                // quad
  const int bglob = (chain << 4) + mr;
  const short* Brow = &Bs[(g * 16 + mr) * BS_STRIDE + q * 8];
  int* mycnt = cnt + chain * SEQ;
  const int er = tid >> 4, ec = tid & 15; // epilogue coords

  for (int t = 0; t < SEQ; ++t) {
    floatx4 acc = {0.f, 0.f, 0.f, 0.f};

    // ---- issue x A-frag loads (h-independent; in flight across the poll)
    const short* xr = xb + ((size_t)t * BATCH + bglob) * DIN + q * 8;
    short8 xaf[8];
#pragma unroll
    for (int kk = 0; kk < 8; ++kk) xaf[kk] = *(const short8*)(xr + kk * 32);

    // ---- wait for full h_{t-1} of this chain
    if (t > 0) {
      if (tid == 0) {
        while (__hip_atomic_load(&mycnt[t - 1], __ATOMIC_RELAXED,
                                 __HIP_MEMORY_SCOPE_AGENT) < NCOLW)
          __builtin_amdgcn_s_sleep(1);
      }
      __syncthreads();
    }

    // ---- issue h A-frag loads (bf16 ring buffer, slot t = h_{t-1})
    const short* hr = hbuf + ((size_t)t * BATCH + bglob) * HID + q * 8;
    short8 haf[16];
#pragma unroll
    for (int kk = 0; kk < 16; ++kk) haf[kk] = *(const short8*)(hr + kk * 32);

    // ---- x @ W MFMAs (overlap h-load latency)
#pragma unroll
    for (int kk = 0; kk < 8; ++kk)
      acc = __builtin_amdgcn_mfma_f32_16x16x32_bf16(
          xaf[kk], *(const short8*)(Brow + kk * 32), acc, 0, 0, 0);

    // ---- h @ U MFMAs
#pragma unroll
    for (int kk = 0; kk < 16; ++kk)
      acc = __builtin_amdgcn_mfma_f32_16x16x32_bf16(
          haf[kk], *(const short8*)(Brow + DIN + kk * 32), acc, 0, 0, 0);

    // ---- epilogue: C/D layout col=lane&15, row=q*4+i (m89)
#pragma unroll
    for (int i = 0; i < 4; ++i) gbuf[g][q * 4 + i][mr] = acc[i];
    __syncthreads();
    {
      float gi = gbuf[0][er][ec] + bias_s[0][ec];
      float gf = gbuf[1][er][ec] + bias_s[1][ec];
      float gc = gbuf[2][er][ec] + bias_s[2][ec];
      float go = gbuf[3][er][ec] + bias_s[3][ec];
      float it = fsig(gi), ft = fsig(gf), ot = fsig(go);
      float ch = ftanh(gc);
      float cn = md_s[er][ec] * (ft * carr[er][ec] + it * ch);
      carr[er][ec] = cn;
      float hv = ot * ftanh(cn);

      // fp32 output (not read by consumers)
      size_t oidx = ((size_t)t * BATCH + (chain << 4) + er) * HID + (j << 4) + ec;
      out[oidx] = hv;
      if (t == SEQ - 1) {
        size_t base = (size_t)SEQ * BATCH * HID;
        int e = ((chain << 4) + er) * HID + (j << 4) + ec;
        out[base + e] = hv;                    // h_T
        out[base + BATCH * HID + e] = cn;      // c_T
      }

      // bf16 ring-buffer store: pair two lanes -> one 4B agent-scope store
      unsigned hb = (unsigned)(unsigned short)f2bf(hv);
      unsigned other = (unsigned)__shfl_xor((int)hb, 1, 64);
      if ((tid & 1) == 0) {
        unsigned pack = hb | (other << 16);
        size_t hidx = ((size_t)(t + 1) * BATCH + (chain << 4) + er) * HID
                      + (j << 4) + ec;         // ec even
        __hip_atomic_store((unsigned*)&hbuf[hidx], pack, __ATOMIC_RELAXED,
                           __HIP_MEMORY_SCOPE_AGENT);
      }
    }
    __syncthreads();  // drains vmcnt for ALL waves before the flag
    if (tid == 0)
      __hip_atomic_fetch_add(&mycnt[t], 1, __ATOMIC_RELAXED,
                             __HIP_MEMORY_SCOPE_AGENT);
  }
}

// ---------------------------------------------------------------------------
extern "C" void kernel_launch(void* const* d_in, const int* in_sizes, int n_in,
                              void* d_out, int out_size, void* d_ws, size_t ws_size,
                              hipStream_t stream) {
  const float* x     = (const float*)d_in[0];
  const float* h0    = (const float*)d_in[1];
  const float* c0    = (const float*)d_in[2];
  const float* alpha = (const float*)d_in[3];
  const float* beta  = (const float*)d_in[4];
  const float* theta = (const float*)d_in[5];
  const float* tspan = (const float*)d_in[6];
  const float* Amd   = (const float*)d_in[7];
  const float* Bmd   = (const float*)d_in[8];
  const float* Cmd   = (const float*)d_in[9];
  const float* Wi = (const float*)d_in[10]; const float* Ui = (const float*)d_in[11];
  const float* bi = (const float*)d_in[12];
  const float* Wf = (const float*)d_in[13]; const float* Uf = (const float*)d_in[14];
  const float* bf_ = (const float*)d_in[15];
  const float* Wc = (const float*)d_in[16]; const float* Uc = (const float*)d_in[17];
  const float* bc = (const float*)d_in[18];
  const float* Wo = (const float*)d_in[19]; const float* Uo = (const float*)d_in[20];
  const float* bo = (const float*)d_in[21];

  float* out = (float*)d_out;
  char* ws = (char*)d_ws;
  // ws layout (bytes):
  short* GT   = (short*)ws;                               // 2048*768*2  = 3,145,728
  float* mdhp = (float*)(ws + 3145728);                   // 65536*4     =   262,144
  int*   cnt  = (int*)(ws + 3145728 + 262144);            // 8*512*4     =    16,384
  short* xb   = (short*)(ws + 3145728 + 262144 + 16384);  // 512*128*256*2 = 33,554,432
  short* hbuf = (short*)(ws + 3145728 + 262144 + 16384 + 33554432); // 513*128*512*2

  zero_cnt<<<16, 256, 0, stream>>>(cnt);
  prep_gt<<<(2048 * KTOT + 255) / 256, 256, 0, stream>>>(Wi, Ui, Wf, Uf, Wc, Uc, Wo, Uo, GT);
  prep_xb<<<16384, 256, 0, stream>>>(x, xb);
  prep_h0<<<256, 256, 0, stream>>>(h0, hbuf);
  prep_mdhp<<<256, 256, 0, stream>>>(alpha, beta, theta, tspan, Amd, Bmd, Cmd, mdhp);
  lstm_persist<<<NCHAIN * NCOLW, 256, 0, stream>>>(xb, c0, bi, bf_, bc, bo,
                                                   GT, mdhp, cnt, hbuf, out);
}